// Round 1
// baseline (7930.444 us; speedup 1.0000x reference)
//
#include <hip/hip_runtime.h>
#include <math.h>

#define T_ 8
#define N_ 100000
#define E_ 1600000
#define F_ 17
#define G_ 32
#define H_ 48

// -------- scatter for conv1: agg[dst][0:17] += x[src][0:17], deg[dst] += 1 ----
__global__ void k_scatter1(const float* __restrict__ x, const int* __restrict__ src,
                           const int* __restrict__ dst, float* __restrict__ deg,
                           float* __restrict__ agg) {
    int idx = blockIdx.x * blockDim.x + threadIdx.x;
    if (idx >= E_ * F_) return;
    int e = idx / F_;
    int k = idx - e * F_;
    int s = src[e], d = dst[e];
    atomicAdd(&agg[d * F_ + k], x[s * F_ + k]);
    if (k == 0) atomicAdd(&deg[d], 1.0f);
}

// -------- conv1: h1 = relu(x@Ws1.T + bs1 + (agg/deg)@Wn1.T + bn1) -------------
__global__ void k_conv1(const float* __restrict__ x, const float* __restrict__ agg,
                        const float* __restrict__ deg,
                        const float* __restrict__ Ws1, const float* __restrict__ bs1,
                        const float* __restrict__ Wn1, const float* __restrict__ bn1,
                        float* __restrict__ h1) {
    int idx = blockIdx.x * blockDim.x + threadIdx.x;
    if (idx >= N_ * H_) return;
    int n = idx / H_;
    int h = idx - n * H_;
    float invdeg = 1.0f / fmaxf(deg[n], 1.0f);
    float acc = bs1[h] + bn1[h];
    const float* xr = x + n * F_;
    const float* ar = agg + n * F_;
    const float* ws = Ws1 + h * F_;
    const float* wn = Wn1 + h * F_;
#pragma unroll
    for (int k = 0; k < F_; ++k)
        acc += xr[k] * ws[k] + ar[k] * invdeg * wn[k];
    h1[idx] = fmaxf(acc, 0.0f);
}

// -------- scatter for conv2: agg[dst][0:48] += h1[src][0:48] ------------------
__global__ void k_scatter2(const float* __restrict__ h1, const int* __restrict__ src,
                           const int* __restrict__ dst, float* __restrict__ agg) {
    int idx = blockIdx.x * blockDim.x + threadIdx.x;
    if (idx >= E_ * H_) return;
    int e = idx / H_;
    int k = idx - e * H_;
    atomicAdd(&agg[dst[e] * H_ + k], h1[src[e] * H_ + k]);
}

// -------- conv2 + spatial mask + pooled accumulation --------------------------
// block = 192 threads = 4 nodes x 48 h-channels
__global__ __launch_bounds__(192) void k_conv2(
        const float* __restrict__ h1, const float* __restrict__ agg,
        const float* __restrict__ deg,
        const float* __restrict__ Ws2, const float* __restrict__ bs2,
        const float* __restrict__ Wn2, const float* __restrict__ bn2,
        const float* __restrict__ Wsm, const float* __restrict__ bsm,
        float* __restrict__ sm_out, float* __restrict__ pooled) {
    __shared__ float sh_h2[4][H_];
    __shared__ float psum[H_];
    int tid = threadIdx.x;
    int ln = tid / H_;
    int h = tid - ln * H_;
    int n = blockIdx.x * 4 + ln;
    if (tid < H_) psum[tid] = 0.0f;
    float h2v = 0.0f;
    if (n < N_) {
        float invdeg = 1.0f / fmaxf(deg[n], 1.0f);
        float acc = bs2[h] + bn2[h];
        const float* hr = h1 + n * H_;
        const float* ar = agg + n * H_;
        const float* ws = Ws2 + h * H_;
        const float* wn = Wn2 + h * H_;
#pragma unroll 8
        for (int k = 0; k < H_; ++k)
            acc += hr[k] * ws[k] + ar[k] * invdeg * wn[k];
        h2v = fmaxf(acc, 0.0f);
        sh_h2[ln][h] = h2v;
    }
    __syncthreads();
    if (n < N_) {
        const float* wm = Wsm + h * H_;
        float acc = bsm[h];
#pragma unroll 8
        for (int k = 0; k < H_; ++k) acc += sh_h2[ln][k] * wm[k];
        float smv = 1.0f / (1.0f + expf(-acc));
        sm_out[(size_t)n * H_ + h] = smv;
        atomicAdd(&psum[h], h2v * smv);
    }
    __syncthreads();
    if (tid < H_) atomicAdd(&pooled[tid], psum[tid]);
}

// -------- tail: seq build, GRU, attention, regressor, top8 --------------------
__global__ void k_final(const float* __restrict__ gf_all, const float* __restrict__ pooled,
                        const float* __restrict__ Wgp, const float* __restrict__ bgp,
                        const float* __restrict__ W_ih, const float* __restrict__ b_ih,
                        const float* __restrict__ W_hh, const float* __restrict__ b_hh,
                        const float* __restrict__ Wa, const float* __restrict__ ba,
                        const float* __restrict__ Wtm, const float* __restrict__ btm,
                        const float* __restrict__ Wr1, const float* __restrict__ br1,
                        const float* __restrict__ Wr2, const float* __restrict__ br2,
                        const float* __restrict__ Ws1,
                        float* __restrict__ out) {
    __shared__ float seq[T_][2 * H_];
    __shared__ float hstate[H_];
    __shared__ float gout[T_][H_];
    __shared__ float tmp[H_];
    __shared__ float scores[T_], tmask[T_], wts[T_];
    __shared__ float ctx[H_], reg[H_];
    int tid = threadIdx.x;  // 64 threads

    if (tid < H_) {
        for (int t = 0; t < T_; ++t) {
            seq[t][tid] = pooled[t * H_ + tid] / (float)N_;
            float acc = bgp[tid];
            for (int k = 0; k < G_; ++k) acc += Wgp[tid * G_ + k] * gf_all[t * G_ + k];
            seq[t][H_ + tid] = fmaxf(acc, 0.0f);
        }
        hstate[tid] = 0.0f;
    }
    __syncthreads();

    for (int t = 0; t < T_; ++t) {
        if (tid < H_) {
            float gi_r = b_ih[tid], gi_z = b_ih[H_ + tid], gi_n = b_ih[2 * H_ + tid];
            for (int k = 0; k < 2 * H_; ++k) {
                float xv = seq[t][k];
                gi_r += W_ih[tid * 2 * H_ + k] * xv;
                gi_z += W_ih[(H_ + tid) * 2 * H_ + k] * xv;
                gi_n += W_ih[(2 * H_ + tid) * 2 * H_ + k] * xv;
            }
            float gh_r = b_hh[tid], gh_z = b_hh[H_ + tid], gh_n = b_hh[2 * H_ + tid];
            for (int k = 0; k < H_; ++k) {
                float hv = hstate[k];
                gh_r += W_hh[tid * H_ + k] * hv;
                gh_z += W_hh[(H_ + tid) * H_ + k] * hv;
                gh_n += W_hh[(2 * H_ + tid) * H_ + k] * hv;
            }
            float r = 1.0f / (1.0f + expf(-(gi_r + gh_r)));
            float z = 1.0f / (1.0f + expf(-(gi_z + gh_z)));
            float nn = tanhf(gi_n + r * gh_n);
            tmp[tid] = (1.0f - z) * nn + z * hstate[tid];
        }
        __syncthreads();
        if (tid < H_) {
            hstate[tid] = tmp[tid];
            gout[t][tid] = tmp[tid];
        }
        __syncthreads();
    }

    if (tid < T_) {
        float s = ba[0], m = btm[0];
        for (int k = 0; k < H_; ++k) {
            s += Wa[k] * gout[tid][k];
            m += Wtm[k] * gout[tid][k];
        }
        scores[tid] = s;
        tmask[tid] = 1.0f / (1.0f + expf(-m));
    }
    __syncthreads();
    if (tid == 0) {
        float mx = scores[0];
        for (int t = 1; t < T_; ++t) mx = fmaxf(mx, scores[t]);
        float sum = 0.0f;
        for (int t = 0; t < T_; ++t) { wts[t] = expf(scores[t] - mx); sum += wts[t]; }
        for (int t = 0; t < T_; ++t) {
            wts[t] /= sum;
            out[1 + t] = wts[t];
            out[17 + (size_t)T_ * N_ * H_ + t] = tmask[t];
        }
    }
    __syncthreads();
    if (tid < H_) {
        float c = 0.0f;
        for (int t = 0; t < T_; ++t) c += gout[t][tid] * wts[t] * tmask[t];
        ctx[tid] = c;
    }
    __syncthreads();
    if (tid < H_) {
        float acc = br1[tid];
        for (int k = 0; k < H_; ++k) acc += Wr1[tid * H_ + k] * ctx[k];
        reg[tid] = fmaxf(acc, 0.0f);
    }
    __syncthreads();
    if (tid == 0) {
        float p = br2[0];
        for (int k = 0; k < H_; ++k) p += Wr2[k] * reg[k];
        out[0] = p;
        // top8 of mean_|Ws1| over rows
        float m[F_];
        for (int f = 0; f < F_; ++f) {
            float s = 0.0f;
            for (int h = 0; h < H_; ++h) s += fabsf(Ws1[h * F_ + f]);
            m[f] = s / (float)H_;
        }
        for (int i = 0; i < 8; ++i) {
            int best = i;
            for (int j = i + 1; j < F_; ++j)
                if (m[j] > m[best]) best = j;
            float tv = m[i]; m[i] = m[best]; m[best] = tv;
            out[9 + i] = m[i];
        }
    }
}

extern "C" void kernel_launch(void* const* d_in, const int* in_sizes, int n_in,
                              void* d_out, int out_size, void* d_ws, size_t ws_size,
                              hipStream_t stream) {
    const float* node_features  = (const float*)d_in[0];
    const int*   edge_index     = (const int*)d_in[1];
    const float* graph_features = (const float*)d_in[2];
    const float* Ws1 = (const float*)d_in[3];
    const float* bs1 = (const float*)d_in[4];
    const float* Wn1 = (const float*)d_in[5];
    const float* bn1 = (const float*)d_in[6];
    const float* Ws2 = (const float*)d_in[7];
    const float* bs2 = (const float*)d_in[8];
    const float* Wn2 = (const float*)d_in[9];
    const float* bn2 = (const float*)d_in[10];
    const float* Wgp = (const float*)d_in[11];
    const float* bgp = (const float*)d_in[12];
    const float* W_ih = (const float*)d_in[13];
    const float* b_ih = (const float*)d_in[14];
    const float* W_hh = (const float*)d_in[15];
    const float* b_hh = (const float*)d_in[16];
    const float* Wa  = (const float*)d_in[17];
    const float* ba  = (const float*)d_in[18];
    const float* Wsm = (const float*)d_in[19];
    const float* bsm = (const float*)d_in[20];
    const float* Wtm = (const float*)d_in[21];
    const float* btm = (const float*)d_in[22];
    const float* Wr1 = (const float*)d_in[23];
    const float* br1 = (const float*)d_in[24];
    const float* Wr2 = (const float*)d_in[25];
    const float* br2 = (const float*)d_in[26];

    float* ws = (float*)d_ws;
    float* deg    = ws;                                  // N
    float* agg    = ws + N_;                             // N*H (used N*F for conv1)
    float* h1     = agg + (size_t)N_ * H_;               // N*H
    float* pooled = h1 + (size_t)N_ * H_;                // T*H

    float* out = (float*)d_out;

    hipMemsetAsync(pooled, 0, T_ * H_ * sizeof(float), stream);

    for (int t = 0; t < T_; ++t) {
        const float* x   = node_features + (size_t)t * N_ * F_;
        const int*   src = edge_index + (size_t)t * 2 * E_;
        const int*   dst = src + E_;

        hipMemsetAsync(deg, 0, N_ * sizeof(float), stream);
        hipMemsetAsync(agg, 0, (size_t)N_ * F_ * sizeof(float), stream);
        k_scatter1<<<(E_ * F_ + 255) / 256, 256, 0, stream>>>(x, src, dst, deg, agg);
        k_conv1<<<(N_ * H_ + 255) / 256, 256, 0, stream>>>(x, agg, deg, Ws1, bs1, Wn1, bn1, h1);
        hipMemsetAsync(agg, 0, (size_t)N_ * H_ * sizeof(float), stream);
        k_scatter2<<<(E_ * H_ + 255) / 256, 256, 0, stream>>>(h1, src, dst, agg);
        float* sm_out = out + 17 + (size_t)t * N_ * H_;
        k_conv2<<<(N_ + 3) / 4, 192, 0, stream>>>(h1, agg, deg, Ws2, bs2, Wn2, bn2,
                                                  Wsm, bsm, sm_out, pooled + t * H_);
    }

    k_final<<<1, 64, 0, stream>>>(graph_features, pooled, Wgp, bgp,
                                  W_ih, b_ih, W_hh, b_hh, Wa, ba, Wtm, btm,
                                  Wr1, br1, Wr2, br2, Ws1, out);
}